// Round 2
// baseline (1058.127 us; speedup 1.0000x reference)
//
#include <hip/hip_runtime.h>
#include <hip/hip_bf16.h>
#include <type_traits>
#include <utility>

// ---------------------------------------------------------------------------
// Problem constants (from reference)
// ---------------------------------------------------------------------------
#define NNODE 8192
#define EE    98304
#define ETOT  (EE + NNODE)     // edges + self-loops
#define GG    64
#define HC    1024             // hidden = H*C
#define NCAT  2048             // [xl | xr] concatenated GEMM output width
#define MAXDEG 128             // Binomial(98304,1/8192): max ~32; 128 is safe
#define SLOPE 0.2f

typedef unsigned short u16;

// ---------------------------------------------------------------------------
// bf16 helpers + dtype-flexible scalar read (flag: 1 = inputs are f32)
// ---------------------------------------------------------------------------
__device__ __forceinline__ float bf2f(u16 u){
  union { unsigned int i; float f; } v; v.i = ((unsigned int)u) << 16; return v.f;
}
__device__ __forceinline__ u16 f2bf(float f){
  unsigned int x = __float_as_uint(f);
  unsigned int r = (x + 0x7fffu + ((x >> 16) & 1u)) >> 16;   // RNE
  return (u16)r;
}
__device__ __forceinline__ float lo16(unsigned int u){ return __uint_as_float(u << 16); }
__device__ __forceinline__ float hi16(unsigned int u){ return __uint_as_float(u & 0xffff0000u); }

__device__ __forceinline__ float rdf(const void* p, int i, int fl){
  return fl ? ((const float*)p)[i] : bf2f(((const u16*)p)[i]);
}

__device__ __forceinline__ void load16bf(const u16* p, float* f){
  uint4 u0 = *(const uint4*)p;
  uint4 u1 = *(const uint4*)(p + 8);
  f[0]=lo16(u0.x); f[1]=hi16(u0.x); f[2]=lo16(u0.y); f[3]=hi16(u0.y);
  f[4]=lo16(u0.z); f[5]=hi16(u0.z); f[6]=lo16(u0.w); f[7]=hi16(u0.w);
  f[8]=lo16(u1.x); f[9]=hi16(u1.x); f[10]=lo16(u1.y); f[11]=hi16(u1.y);
  f[12]=lo16(u1.z); f[13]=hi16(u1.z); f[14]=lo16(u1.w); f[15]=hi16(u1.w);
}

// ---------------------------------------------------------------------------
// dtype sniff: words of f32 N(0,1) have exponent field in [97,158]; u16-pair
// (bf16) words essentially never do. flag=1 -> inputs are float32.
// ---------------------------------------------------------------------------
__global__ void sniff_kernel(const unsigned int* __restrict__ x, int* __restrict__ flag){
  __shared__ int cnt;
  if (threadIdx.x == 0) cnt = 0;
  __syncthreads();
  const unsigned int w = x[threadIdx.x];
  const int e = (w >> 23) & 0xFF;
  if (e >= 97 && e <= 158) atomicAdd(&cnt, 1);
  __syncthreads();
  if (threadIdx.x == 0) *flag = (cnt > 128) ? 1 : 0;
}

__global__ void convert_kernel(const void* __restrict__ src, u16* __restrict__ dst,
                               int n, const int* __restrict__ flag){
  const int i = blockIdx.x * 256 + threadIdx.x;
  if (i >= n) return;
  dst[i] = (*flag) ? f2bf(((const float*)src)[i]) : ((const u16*)src)[i];
}

// ---------------------------------------------------------------------------
// MFMA plumbing (signature probe: <8 x __bf16> vs <8 x short>)
// ---------------------------------------------------------------------------
typedef float  f32x4 __attribute__((ext_vector_type(4)));
typedef __bf16 b16x8 __attribute__((ext_vector_type(8)));
typedef short  s16x8 __attribute__((ext_vector_type(8)));

template <typename V, typename = void> struct MfmaOk : std::false_type {};
template <typename V>
struct MfmaOk<V, std::void_t<decltype(__builtin_amdgcn_mfma_f32_16x16x32_bf16(
    std::declval<V>(), std::declval<V>(), std::declval<f32x4>(), 0, 0, 0))>>
    : std::true_type {};

using frag_t = std::conditional_t<MfmaOk<b16x8>::value, b16x8, s16x8>;

__device__ __forceinline__ f32x4 mfma16(frag_t a, frag_t b, f32x4 c){
  return __builtin_amdgcn_mfma_f32_16x16x32_bf16(a, b, c, 0, 0, 0);
}

// ---------------------------------------------------------------------------
// GEMM: C[8192][2048] = A[8192][K] * Bt[2048][K]^T + bias  (bf16 in/out)
// 128x128 tile, 4 waves (2x2), wave = 4x4 of 16x16x32 mfma, BK=64.
// Register staging: coalesced uint4 global loads -> ds_write_b128 into
// XOR-swizzled layout LDS[r][s] = global chunk s^(r&7)  (2-way banks = free).
// C/D layout (m89-verified): col = lane&15, row = (lane>>4)*4 + reg.
// ---------------------------------------------------------------------------
__global__ __launch_bounds__(256) void gemm_bt(
    const u16* __restrict__ A, const u16* __restrict__ Bt,
    const float* __restrict__ bias, u16* __restrict__ C, int K)
{
  __shared__ __align__(16) u16 lA[128 * 64];
  __shared__ __align__(16) u16 lB[128 * 64];
  const int tid = threadIdx.x, lane = tid & 63;
  const int wid = tid >> 6;
  const int m0 = blockIdx.y * 128, n0 = blockIdx.x * 128;
  const int wm = (wid >> 1) * 64, wn = (wid & 1) * 64;

  f32x4 acc[4][4];
  #pragma unroll
  for (int i = 0; i < 4; i++)
    #pragma unroll
    for (int j = 0; j < 4; j++)
      #pragma unroll
      for (int r = 0; r < 4; r++) acc[i][j][r] = 0.f;

  // staging coords: thread covers rows t*32+srow (t=0..3), global chunk scs
  const int srow = tid >> 3;            // 0..31
  const int scs  = tid & 7;             // contiguous 16B chunks per row
  const int wslot = scs ^ (srow & 7);   // swizzled LDS slot (row&7 == srow&7)
  const u16* ga = A  + (size_t)(m0 + srow) * K + scs * 8;
  const u16* gb = Bt + (size_t)(n0 + srow) * K + scs * 8;
  u16* la = lA + srow * 64 + wslot * 8;
  u16* lb = lB + srow * 64 + wslot * 8;

  const int fr = lane & 15, q = lane >> 4;

  for (int k0 = 0; k0 < K; k0 += 64) {
    uint4 ra[4], rb[4];
    #pragma unroll
    for (int t = 0; t < 4; t++) {
      ra[t] = *(const uint4*)(ga + (size_t)t * 32 * K + k0);
      rb[t] = *(const uint4*)(gb + (size_t)t * 32 * K + k0);
    }
    __syncthreads();                   // prev iter's LDS reads done
    #pragma unroll
    for (int t = 0; t < 4; t++) {
      *(uint4*)(la + t * 32 * 64) = ra[t];
      *(uint4*)(lb + t * 32 * 64) = rb[t];
    }
    __syncthreads();                   // staging visible
    #pragma unroll
    for (int ks = 0; ks < 2; ks++) {
      const int cb = ks * 4 + q;
      frag_t af[4], bf[4];
      #pragma unroll
      for (int i = 0; i < 4; i++) {
        int r = wm + i * 16 + fr;
        af[i] = *(const frag_t*)(lA + r * 64 + (cb ^ (r & 7)) * 8);
      }
      #pragma unroll
      for (int j = 0; j < 4; j++) {
        int r = wn + j * 16 + fr;
        bf[j] = *(const frag_t*)(lB + r * 64 + (cb ^ (r & 7)) * 8);
      }
      #pragma unroll
      for (int i = 0; i < 4; i++)
        #pragma unroll
        for (int j = 0; j < 4; j++)
          acc[i][j] = mfma16(af[i], bf[j], acc[i][j]);
    }
  }

  #pragma unroll
  for (int i = 0; i < 4; i++) {
    const int gm0 = m0 + wm + i * 16 + q * 4;
    #pragma unroll
    for (int j = 0; j < 4; j++) {
      const int gn = n0 + wn + j * 16 + fr;
      const float bj = bias[gn];
      #pragma unroll
      for (int r = 0; r < 4; r++)
        C[(size_t)(gm0 + r) * NCAT + gn] = f2bf(acc[i][j][r] + bj);
    }
  }
}

// ---------------------------------------------------------------------------
// Weight transpose: in [K][1024] (+off) -> out [1024][K] bf16, dtype-flex.
// ---------------------------------------------------------------------------
__global__ void transpose_w(const void* __restrict__ in, int off,
                            u16* __restrict__ out, int K,
                            const int* __restrict__ flag){
  __shared__ u16 tile[32][33];
  const int fl = *flag;
  const int n0 = blockIdx.x * 32, k0 = blockIdx.y * 32;
  const int x = threadIdx.x, y = threadIdx.y;
  for (int i = y; i < 32; i += 8){
    const int idx = off + (k0 + i) * 1024 + n0 + x;
    tile[i][x] = fl ? f2bf(((const float*)in)[idx]) : ((const u16*)in)[idx];
  }
  __syncthreads();
  for (int i = y; i < 32; i += 8) out[(size_t)(n0 + i) * K + k0 + x] = tile[x][i];
}

__global__ void bias_prep(const void* __restrict__ bl0, const void* __restrict__ br0,
                          const void* __restrict__ bl, const void* __restrict__ br,
                          float* __restrict__ ball, const int* __restrict__ flag){
  const int i = blockIdx.x * 256 + threadIdx.x;
  if (i >= 4 * 2048) return;
  const int fl = *flag;
  const int l = i >> 11, j = i & 2047;
  float v;
  if (l == 0) v = (j < 1024) ? rdf(bl0, j, fl) : rdf(br0, j - 1024, fl);
  else        v = (j < 1024) ? rdf(bl, (l - 1) * 1024 + j, fl)
                             : rdf(br, (l - 1) * 1024 + (j - 1024), fl);
  ball[i] = v;
}

// ---------------------------------------------------------------------------
// CSR by dst (edges + self-loops), rebuilt every call.
// ---------------------------------------------------------------------------
__global__ void count_kernel(const int* __restrict__ edge, int* __restrict__ cnt){
  const int i = blockIdx.x * 256 + threadIdx.x;
  if (i >= ETOT) return;
  const int d = (i < EE) ? edge[EE + i] : (i - EE);
  atomicAdd(&cnt[d], 1);
}

__global__ __launch_bounds__(1024) void scan_kernel(const int* __restrict__ cnt,
    int* __restrict__ rowptr, int* __restrict__ fillpos){
  __shared__ int sc[1024];
  const int t = threadIdx.x;
  int loc[8]; int s = 0;
  #pragma unroll
  for (int i = 0; i < 8; i++){ loc[i] = cnt[t * 8 + i]; s += loc[i]; }
  sc[t] = s; __syncthreads();
  for (int off = 1; off < 1024; off <<= 1){
    int v = (t >= off) ? sc[t - off] : 0;
    __syncthreads();
    sc[t] += v;
    __syncthreads();
  }
  int base = sc[t] - s;   // exclusive prefix
  #pragma unroll
  for (int i = 0; i < 8; i++){ rowptr[t * 8 + i] = base; fillpos[t * 8 + i] = base; base += loc[i]; }
  if (t == 1023) rowptr[NNODE] = base;
}

__global__ void fill_kernel(const int* __restrict__ edge, int* __restrict__ fillpos,
                            int* __restrict__ csr){
  const int i = blockIdx.x * 256 + threadIdx.x;
  if (i >= ETOT) return;
  int s, d;
  if (i < EE){ s = edge[i]; d = edge[EE + i]; } else { s = d = i - EE; }
  const int p = atomicAdd(&fillpos[d], 1);
  csr[p] = s;
}

// ---------------------------------------------------------------------------
// Fused per-node GATv2: logits -> softmax -> aggregate -> bias+ReLU+LN(+res).
// One block (256 thr) per dst node. xlr = [xl | xr] rows of 2048 bf16.
// ---------------------------------------------------------------------------
__global__ __launch_bounds__(256) void node_kernel(
    const u16* __restrict__ xlr, const u16* __restrict__ hprev,
    const int* __restrict__ rowptr, const int* __restrict__ csr,
    const void* __restrict__ attw, int att_off,
    const void* __restrict__ gatb, int gatb_off,
    const void* __restrict__ lng, int lng_off,
    const void* __restrict__ lnb, int lnb_off,
    const int* __restrict__ flag, u16* __restrict__ hout)
{
  const int d = blockIdx.x;
  const int tid = threadIdx.x, lane = tid & 63, wid = tid >> 6;
  const int fl = *flag;
  const int rs = rowptr[d];
  int deg = rowptr[d + 1] - rs;
  if (deg > MAXDEG) deg = MAXDEG;

  __shared__ float s_alpha[MAXDEG * 8];
  __shared__ int   s_src[MAXDEG];
  __shared__ float s_red[8];

  // per-lane 16-channel slice of xr[d] and att (head = lane>>3)
  float xr[16], at[16];
  load16bf(xlr + (size_t)d * NCAT + HC + lane * 16, xr);
  if (fl){
    const float* ap = (const float*)attw + att_off + lane * 16;
    #pragma unroll
    for (int i = 0; i < 16; i++) at[i] = ap[i];
  } else {
    load16bf((const u16*)attw + att_off + lane * 16, at);
  }
  const int h = lane >> 3;

  // logits: wave w handles edges ei ≡ w (mod 4)
  for (int ei = wid; ei < deg; ei += 4){
    const int s = csr[rs + ei];
    if (lane == 0) s_src[ei] = s;
    float xv[16];
    load16bf(xlr + (size_t)s * NCAT + lane * 16, xv);
    float p = 0.f;
    #pragma unroll
    for (int i = 0; i < 16; i++){
      float v = xv[i] + xr[i];
      v = (v > 0.f) ? v : SLOPE * v;
      p += v * at[i];
    }
    p += __shfl_xor(p, 1); p += __shfl_xor(p, 2); p += __shfl_xor(p, 4);
    if ((lane & 7) == 0) s_alpha[ei * 8 + h] = p;
  }
  __syncthreads();

  // softmax per head (deg ~ 13 — serial is fine)
  if (tid < 8){
    float m = -1e30f;
    for (int ei = 0; ei < deg; ei++) m = fmaxf(m, s_alpha[ei * 8 + tid]);
    float ss = 0.f;
    for (int ei = 0; ei < deg; ei++){
      float ev = __expf(s_alpha[ei * 8 + tid] - m);
      s_alpha[ei * 8 + tid] = ev; ss += ev;
    }
    const float inv = 1.f / ss;
    for (int ei = 0; ei < deg; ei++) s_alpha[ei * 8 + tid] *= inv;
  }
  __syncthreads();

  // aggregate: out[d][c] = sum_e alpha[e][head(c)] * xl[src][c]; 4 ch/thread
  const int c0 = tid * 4;
  const int hh = tid >> 5;
  float z0 = 0, z1 = 0, z2 = 0, z3 = 0;
  for (int ei = 0; ei < deg; ei++){
    const int s = s_src[ei];
    const float a = s_alpha[ei * 8 + hh];
    const uint2 u = *(const uint2*)(xlr + (size_t)s * NCAT + c0);
    z0 += a * lo16(u.x); z1 += a * hi16(u.x);
    z2 += a * lo16(u.y); z3 += a * hi16(u.y);
  }

  // +bias, ReLU, LayerNorm, gamma/beta, +residual
  z0 = fmaxf(z0 + rdf(gatb, gatb_off + c0 + 0, fl), 0.f);
  z1 = fmaxf(z1 + rdf(gatb, gatb_off + c0 + 1, fl), 0.f);
  z2 = fmaxf(z2 + rdf(gatb, gatb_off + c0 + 2, fl), 0.f);
  z3 = fmaxf(z3 + rdf(gatb, gatb_off + c0 + 3, fl), 0.f);
  float sum = z0 + z1 + z2 + z3;
  float sq  = z0 * z0 + z1 * z1 + z2 * z2 + z3 * z3;
  #pragma unroll
  for (int off = 1; off < 64; off <<= 1){ sum += __shfl_xor(sum, off); sq += __shfl_xor(sq, off); }
  if (lane == 0){ s_red[wid] = sum; s_red[4 + wid] = sq; }
  __syncthreads();
  const float tsum = s_red[0] + s_red[1] + s_red[2] + s_red[3];
  const float tsq  = s_red[4] + s_red[5] + s_red[6] + s_red[7];
  const float mean = tsum * (1.f / 1024.f);
  const float var  = tsq * (1.f / 1024.f) - mean * mean;
  const float rstd = rsqrtf(var + 1e-5f);
  float y0 = (z0 - mean) * rstd * rdf(lng, lng_off + c0 + 0, fl) + rdf(lnb, lnb_off + c0 + 0, fl);
  float y1 = (z1 - mean) * rstd * rdf(lng, lng_off + c0 + 1, fl) + rdf(lnb, lnb_off + c0 + 1, fl);
  float y2 = (z2 - mean) * rstd * rdf(lng, lng_off + c0 + 2, fl) + rdf(lnb, lnb_off + c0 + 2, fl);
  float y3 = (z3 - mean) * rstd * rdf(lng, lng_off + c0 + 3, fl) + rdf(lnb, lnb_off + c0 + 3, fl);
  if (hprev){
    const uint2 u = *(const uint2*)(hprev + (size_t)d * HC + c0);
    y0 += lo16(u.x); y1 += hi16(u.x); y2 += lo16(u.y); y3 += hi16(u.y);
  }
  uint2 o;
  o.x = (unsigned)f2bf(y0) | ((unsigned)f2bf(y1) << 16);
  o.y = (unsigned)f2bf(y2) | ((unsigned)f2bf(y3) << 16);
  *(uint2*)(hout + (size_t)d * HC + c0) = o;
}

// ---------------------------------------------------------------------------
// Mean pool per graph (batch sorted -> binary search) + Temb concat
// ---------------------------------------------------------------------------
__device__ __forceinline__ int lbound(const int* a, int n, int v){
  int lo = 0, hi = n;
  while (lo < hi){ int mid = (lo + hi) >> 1; if (a[mid] < v) lo = mid + 1; else hi = mid; }
  return lo;
}

__global__ __launch_bounds__(256) void pool_kernel(const u16* __restrict__ hfin,
    const int* __restrict__ batch, const int* __restrict__ ytype,
    const void* __restrict__ temb, const int* __restrict__ flag,
    float* __restrict__ gfeat)
{
  const int g = blockIdx.x, t = threadIdx.x;
  const int s = lbound(batch, NNODE, g);
  const int e = lbound(batch, NNODE, g + 1);
  float a0 = 0, a1 = 0, a2 = 0, a3 = 0;
  for (int n = s; n < e; n++){
    const uint2 u = *(const uint2*)(hfin + (size_t)n * HC + t * 4);
    a0 += lo16(u.x); a1 += hi16(u.x); a2 += lo16(u.y); a3 += hi16(u.y);
  }
  const float inv = 1.f / fmaxf((float)(e - s), 1.f);
  float* gp = gfeat + g * 1040 + t * 4;
  gp[0] = a0 * inv; gp[1] = a1 * inv; gp[2] = a2 * inv; gp[3] = a3 * inv;
  if (t < 16) gfeat[g * 1040 + 1024 + t] = rdf(temb, ytype[g] * 16 + t, *flag);
}

// ---------------------------------------------------------------------------
// Heads: out_fam[64][64], out_type[64][32]; store width follows input dtype
// ---------------------------------------------------------------------------
__global__ __launch_bounds__(128) void head_kernel(const float* __restrict__ gfeat,
    const void* __restrict__ wfam, const void* __restrict__ bfam,
    const void* __restrict__ wtyp, const void* __restrict__ btyp,
    const int* __restrict__ flag, void* __restrict__ outp)
{
  const int g = blockIdx.x, t = threadIdx.x;
  const int fl = *flag;
  __shared__ float gf[1040];
  for (int i = t; i < 1040; i += 128) gf[i] = gfeat[g * 1040 + i];
  __syncthreads();
  if (t < 64){
    float a = rdf(bfam, t, fl);
    for (int k = 0; k < 1040; k++) a += gf[k] * rdf(wfam, k * 64 + t, fl);
    if (fl) ((float*)outp)[g * 64 + t] = a;
    else    ((u16*)outp)[g * 64 + t] = f2bf(a);
  } else if (t < 96){
    const int j = t - 64;
    float a = rdf(btyp, j, fl);
    for (int k = 0; k < 1040; k++) a += gf[k] * rdf(wtyp, k * 32 + j, fl);
    if (fl) ((float*)outp)[4096 + g * 32 + j] = a;
    else    ((u16*)outp)[4096 + g * 32 + j] = f2bf(a);
  }
}

// ---------------------------------------------------------------------------
// Orchestration
// ---------------------------------------------------------------------------
extern "C" void kernel_launch(void* const* d_in, const int* in_sizes, int n_in,
                              void* d_out, int out_size, void* d_ws, size_t ws_size,
                              hipStream_t stream)
{
  (void)in_sizes; (void)n_in; (void)out_size; (void)ws_size;
  const void* x    = d_in[0];
  const int* edge  = (const int*)d_in[1];
  const int* batch = (const int*)d_in[2];
  const int* ytyp  = (const int*)d_in[3];
  const void* Wl0  = d_in[4];
  const void* bl0  = d_in[5];
  const void* Wr0  = d_in[6];
  const void* br0  = d_in[7];
  const void* att0 = d_in[8];
  const void* b0   = d_in[9];
  const void* Wl   = d_in[10];
  const void* bl   = d_in[11];
  const void* Wr   = d_in[12];
  const void* br   = d_in[13];
  const void* att  = d_in[14];
  const void* bg   = d_in[15];
  const void* lng  = d_in[16];
  const void* lnb  = d_in[17];
  const void* temb = d_in[18];
  const void* wfam = d_in[19];
  const void* bfam = d_in[20];
  const void* wtyp = d_in[21];
  const void* btyp = d_in[22];

  char* w = (char*)d_ws;
  auto alloc = [&](size_t b){ char* p = w; w += (b + 255) & ~(size_t)255; return (void*)p; };
  u16* bt[4];
  bt[0] = (u16*)alloc((size_t)2048 * 128 * 2);
  for (int l = 1; l < 4; l++) bt[l] = (u16*)alloc((size_t)2048 * 1024 * 2);
  float* ball = (float*)alloc((size_t)4 * 2048 * 4);
  u16* xbf = (u16*)alloc((size_t)NNODE * 128 * 2);
  u16* xlr = (u16*)alloc((size_t)NNODE * NCAT * 2);
  u16* hA  = (u16*)alloc((size_t)NNODE * HC * 2);
  u16* hB  = (u16*)alloc((size_t)NNODE * HC * 2);
  int* cnt     = (int*)alloc((size_t)NNODE * 4);
  int* rowptr  = (int*)alloc((size_t)(NNODE + 1) * 4);
  int* fillpos = (int*)alloc((size_t)NNODE * 4);
  int* csr     = (int*)alloc((size_t)ETOT * 4);
  float* gfeat = (float*)alloc((size_t)GG * 1040 * 4);
  int* flag    = (int*)alloc(256);

  // dtype sniff + x conversion
  sniff_kernel<<<1, 256, 0, stream>>>((const unsigned int*)x, flag);
  convert_kernel<<<(NNODE * 128 + 255) / 256, 256, 0, stream>>>(x, xbf, NNODE * 128, flag);

  // CSR build
  (void)hipMemsetAsync(cnt, 0, NNODE * 4, stream);
  count_kernel<<<(ETOT + 255) / 256, 256, 0, stream>>>(edge, cnt);
  scan_kernel<<<1, 1024, 0, stream>>>(cnt, rowptr, fillpos);
  fill_kernel<<<(ETOT + 255) / 256, 256, 0, stream>>>(edge, fillpos, csr);

  // weight prep: Bt[l] = [Wl^T ; Wr^T], bias concat (dtype-flex readers)
  bias_prep<<<(4 * 2048) / 256, 256, 0, stream>>>(bl0, br0, bl, br, ball, flag);
  transpose_w<<<dim3(32, 4), dim3(32, 8), 0, stream>>>(Wl0, 0, bt[0], 128, flag);
  transpose_w<<<dim3(32, 4), dim3(32, 8), 0, stream>>>(Wr0, 0, bt[0] + (size_t)1024 * 128, 128, flag);
  for (int l = 1; l < 4; l++){
    transpose_w<<<dim3(32, 32), dim3(32, 8), 0, stream>>>(Wl, (l - 1) * 1024 * 1024, bt[l], 1024, flag);
    transpose_w<<<dim3(32, 32), dim3(32, 8), 0, stream>>>(Wr, (l - 1) * 1024 * 1024,
                                                          bt[l] + (size_t)1024 * 1024, 1024, flag);
  }

  // layer 0 (K=128, no residual)
  gemm_bt<<<dim3(16, 64), 256, 0, stream>>>(xbf, bt[0], ball, xlr, 128);
  node_kernel<<<NNODE, 256, 0, stream>>>(xlr, nullptr, rowptr, csr,
                                         att0, 0, b0, 0, lng, 0, lnb, 0, flag, hA);

  // layers 1..3 (K=1024, residual)
  u16* hcur = hA; u16* hnext = hB;
  for (int l = 1; l < 4; l++){
    gemm_bt<<<dim3(16, 64), 256, 0, stream>>>(hcur, bt[l], ball + l * 2048, xlr, 1024);
    node_kernel<<<NNODE, 256, 0, stream>>>(xlr, hcur, rowptr, csr,
                                           att, (l - 1) * 1024,
                                           bg, (l - 1) * 1024,
                                           lng, l * 1024, lnb, l * 1024, flag, hnext);
    u16* t2 = hcur; hcur = hnext; hnext = t2;
  }

  // pool + heads
  pool_kernel<<<GG, 256, 0, stream>>>(hcur, batch, ytyp, temb, flag, gfeat);
  head_kernel<<<GG, 128, 0, stream>>>(gfeat, wfam, bfam, wtyp, btyp, flag, (void*)d_out);
}